// Round 3
// baseline (617.777 us; speedup 1.0000x reference)
//
#include <hip/hip_runtime.h>
#include <stdint.h>

// Conv2d(64->128,3x3,VALID)+BN+scale, implicit-GEMM bf16 MFMA.
// v4: weights RESIDENT in LDS (A = 64 out-ch half, 73.7 KB, staged once per
// block) + 5-slot rolling xt row buffer (80 KB). Inner loop is pure LDS+MFMA,
// no global loads -> removes the L2-BW/latency bound that pinned MfmaUtil at 12%.
// Block = (n, ch-half, 32-row strip); 2 output rows per iteration; grid = 256
// = exactly 1 block/CU. Row r+4 staged via global_load_lds at iter start,
// row r+5 after a mid-sweep barrier (slot-recycling audited race-free).
// Both xt and Wb are pre-XOR-swizzled in global so LDS reads are conflict-free
// while global_load_lds destinations stay linear. Epilogue: nontemporal stores.

typedef __attribute__((ext_vector_type(8))) short bf16x8;   // 8 bf16, 4 VGPRs
typedef __attribute__((ext_vector_type(4))) float f32x4;

#define C_IN   64
#define HW     128
#define K_OUT  128
#define QO     126
#define PQ     15876        // 126*126
#define ROWB   16384        // bytes per xt row: 128 px * 128 B
#define ABASE  81920        // 5 slots * 16384
#define AHALF  73728        // 64 ch * 576 k * 2 B
#define LDSSZ  155648       // ABASE + AHALF
#define NBLK   256          // 32 n * 2 half * 4 strips = 1 block/CU

__device__ __forceinline__ uint32_t f2bf(float f) {
    uint32_t u = __builtin_bit_cast(uint32_t, f);
    return (u + 0x7FFFu + ((u >> 16) & 1u)) >> 16;   // RNE
}
__device__ __forceinline__ uint32_t pack2(float a, float b) {
    return f2bf(a) | (f2bf(b) << 16);
}
__device__ __forceinline__ void gload_lds16(const void* g, void* l) {
    __builtin_amdgcn_global_load_lds(
        (const __attribute__((address_space(1))) void*)g,
        (__attribute__((address_space(3))) void*)l, 16, 0, 0);
}
// stage one 16 KB xt row: 4 passes of 256 threads x 16 B (dst linear)
__device__ __forceinline__ void stage_row(const char* src_row, char* lds_row) {
    #pragma unroll
    for (int i = 0; i < 4; ++i)
        gload_lds16(src_row + i * 4096, lds_row + i * 4096);
}
__device__ __forceinline__ int m5(int v) { return v - (v / 5) * 5; }

// ---------- pre-pass 1: x NCHW f32 -> xt NHWC bf16, swizzle baked ----------
// Pixel (n,h,w): 128 B of 64 bf16 channels; dword cp stored at cp ^ ((w&7)<<2).
__global__ __launch_bounds__(256)
void xpose_kernel(const float* __restrict__ x, uint32_t* __restrict__ xt) {
    __shared__ float tile[HW][C_IN + 1];      // [w][c], pad -> conflict-free
    const int n   = blockIdx.x >> 7;
    const int h   = blockIdx.x & 127;
    const int tid = threadIdx.x;
    #pragma unroll
    for (int it = 0; it < 32; ++it) {
        int idx = it * 256 + tid;
        int c = idx >> 7, w = idx & 127;
        tile[w][c] = x[((n * C_IN + c) * HW + h) * HW + w];   // coalesced over w
    }
    __syncthreads();
    #pragma unroll
    for (int it = 0; it < 16; ++it) {
        int idx = it * 256 + tid;
        int w = idx >> 5, cp = idx & 31;
        xt[((n * HW + h) * HW + w) * 32 + (cp ^ ((w & 7) << 2))] =
            pack2(tile[w][cp * 2], tile[w][cp * 2 + 1]);      // 128B-coalesced
    }
}

// ---------- pre-pass 2: W -> bf16 [half][m][tap][c] (XOR-swizzled); alpha/beta --
__global__ __launch_bounds__(64)
void wprep_kernel(const float* __restrict__ W, const float* __restrict__ Bb,
                  const float* __restrict__ rmean, const float* __restrict__ rvar,
                  const float* __restrict__ bnw, const float* __restrict__ bnb,
                  const float* __restrict__ scl,
                  unsigned short* __restrict__ Wb,
                  float* __restrict__ alpha, float* __restrict__ beta) {
    const int o = blockIdx.x;       // out-channel 0..127
    const int c = threadIdx.x;      // in-channel 0..63
    const int hf = o >> 6, m = o & 63;
    #pragma unroll
    for (int t = 0; t < 9; ++t) {
        int adr = (m * 1152 + t * 128 + c * 2) ^ ((m & 7) << 4);  // byte, even
        Wb[(hf * AHALF + adr) >> 1] = (unsigned short)f2bf(W[(o * 64 + c) * 9 + t]);
    }
    if (c == 0) {
        float sc = scl[0];
        float a = rsqrtf(rvar[o] + 1e-5f) * bnw[o] * sc;
        alpha[o] = a;
        beta[o]  = (Bb[o] - rmean[o]) * a + bnb[o] * sc;
    }
}

// ---------- main: block = (n, ch-half, 32-row strip), 4 waves, A-resident LDS --
__global__ __launch_bounds__(256, 1)
void conv_main_kernel(const char* __restrict__ xt, const char* __restrict__ wb,
                      const float* __restrict__ alpha, const float* __restrict__ beta,
                      float* __restrict__ out) {
    extern __shared__ __align__(16) char ls[];     // 155648 B

    const int tid  = threadIdx.x;
    const int lane = tid & 63;
    const int wid  = tid >> 6;
    const int wr   = wid >> 1;       // output row within pair (0/1)
    const int wn   = wid & 1;        // px half (0/1)
    const int quad = lane >> 4, l16 = lane & 15;

    // XCD swizzle: wg pairs (2k,2k+1) = two ch-halves of same (n,strip) -> same XCD
    const int wg    = (blockIdx.x & 7) * 32 + (blockIdx.x >> 3);
    const int hf    = wg & 1;
    const int t2    = wg >> 1;           // 0..127
    const int n     = t2 >> 2;
    const int strip = t2 & 3;
    const int p0    = strip * 32;
    const int niter = (strip < 3) ? 16 : 15;   // 2 rows per iter

    const char* src = xt + (size_t)(n * HW + p0) * ROWB;
    const char* wbh = wb + hf * AHALF;
    const int   toff = tid << 4;

    // ---- prologue: A half (18 segs) + B rows 0..3 -> slots 0..3
    #pragma unroll
    for (int j = 0; j < 18; ++j)
        gload_lds16(wbh + j * 4096 + toff, ls + ABASE + j * 4096 + toff);
    #pragma unroll
    for (int rr = 0; rr < 4; ++rr)
        stage_row(src + rr * ROWB + toff, ls + rr * ROWB + toff);

    // ---- A LDS fragment bases: lane m=l16 (+16*ms), k=quad*8 (+cc*32)
    const int swzA = (l16 & 7) << 4;
    int aB[4];
    #pragma unroll
    for (int ms = 0; ms < 4; ++ms)
        aB[ms] = ABASE + (ms * 16 + l16) * 1152 + quad * 16;

    // ---- B in-row offsets per (ns, s): pixel w=q+s; parity toggles bit6
    int bOf[4][3];
    #pragma unroll
    for (int ns = 0; ns < 4; ++ns) {
        const int q = wn * 64 + ns * 16 + l16;
        #pragma unroll
        for (int s = 0; s < 3; ++s) {
            int w = q + s;           // up to 129: spills into A region, lanes discarded
            bOf[ns][s] = w * 128 + ((quad * 16) ^ ((w & 7) << 4));
        }
    }

    f32x4 acc[4][4];
    #pragma unroll
    for (int a = 0; a < 4; ++a)
        #pragma unroll
        for (int b = 0; b < 4; ++b)
            acc[a][b] = (f32x4){0.f, 0.f, 0.f, 0.f};

    __syncthreads();   // prologue staging complete

    #pragma unroll 1
    for (int i = 0; i < niter; ++i) {
        const int r0 = 2 * i;
        const int sbs[3] = { m5(r0 + wr) * ROWB, m5(r0 + wr + 1) * ROWB,
                             m5(r0 + wr + 2) * ROWB };
        const bool st = (i < niter - 1);
        if (st)   // row r0+4 -> slot (r0+4)%5 (= row r0-1's slot, retired last iter)
            stage_row(src + (size_t)(r0 + 4) * ROWB + toff,
                      ls + m5(r0 + 4) * ROWB + toff);

        bf16x8 Af[2][4], Bf[2][4];
        #pragma unroll
        for (int ms = 0; ms < 4; ++ms)
            Af[0][ms] = *(const bf16x8*)(ls + (aB[ms] ^ swzA));
        #pragma unroll
        for (int ns = 0; ns < 4; ++ns)
            Bf[0][ns] = *(const bf16x8*)(ls + sbs[0] + bOf[ns][0]);

        #pragma unroll
        for (int cc = 0; cc < 18; ++cc) {
            const int cur = cc & 1, nxt = cur ^ 1;
            if (cc < 17) {
                const int c2  = cc + 1;
                const int tap = c2 >> 1;
                const int r   = tap / 3;
                const int s   = tap - r * 3;
                #pragma unroll
                for (int ms = 0; ms < 4; ++ms)
                    Af[nxt][ms] = *(const bf16x8*)(ls + ((aB[ms] + c2 * 64) ^ swzA));
                #pragma unroll
                for (int ns = 0; ns < 4; ++ns)
                    Bf[nxt][ns] = *(const bf16x8*)(ls + sbs[r] +
                                      (bOf[ns][s] ^ ((c2 & 1) ? 64 : 0)));
            }
            #pragma unroll
            for (int ms = 0; ms < 4; ++ms)
                #pragma unroll
                for (int ns = 0; ns < 4; ++ns)
                    acc[ms][ns] = __builtin_amdgcn_mfma_f32_16x16x32_bf16(
                        Af[cur][ms], Bf[cur][ns], acc[ms][ns], 0, 0, 0);
            if (cc == 5) {
                // r=0 chunks done reading row r0's slot -> safe to overwrite
                __syncthreads();
                if (st)   // row r0+5 -> slot (r0+5)%5 = (r0)%5
                    stage_row(src + (size_t)(r0 + 5) * ROWB + toff,
                              ls + m5(r0) * ROWB + toff);
            }
        }

        // ---- epilogue: out[n][k][p][q]; C/D: col(px)=l16, row(ch)=quad*4+rr
        const int p = p0 + r0 + wr;
        f32x4 alv[4], bev[4];
        #pragma unroll
        for (int ms = 0; ms < 4; ++ms) {
            const int kk = hf * 64 + ms * 16 + quad * 4;
            alv[ms] = *(const f32x4*)(alpha + kk);
            bev[ms] = *(const f32x4*)(beta + kk);
        }
        #pragma unroll
        for (int ns = 0; ns < 4; ++ns) {
            const int q = wn * 64 + ns * 16 + l16;
            if (q < QO) {
                #pragma unroll
                for (int ms = 0; ms < 4; ++ms) {
                    const int kk = hf * 64 + ms * 16 + quad * 4;
                    #pragma unroll
                    for (int rr = 0; rr < 4; ++rr)
                        __builtin_nontemporal_store(
                            acc[ms][ns][rr] * alv[ms][rr] + bev[ms][rr],
                            &out[((n * K_OUT + kk + rr) * QO + p) * QO + q]);
                }
            }
            #pragma unroll
            for (int ms = 0; ms < 4; ++ms)
                acc[ms][ns] = (f32x4){0.f, 0.f, 0.f, 0.f};
        }

        if (st) __syncthreads();   // staged rows visible; slots safe to recycle
    }
}

extern "C" void kernel_launch(void* const* d_in, const int* in_sizes, int n_in,
                              void* d_out, int out_size, void* d_ws, size_t ws_size,
                              hipStream_t stream) {
    const float* x     = (const float*)d_in[0];
    const float* Wt    = (const float*)d_in[1];
    const float* Bb    = (const float*)d_in[2];
    const float* rmean = (const float*)d_in[3];
    const float* rvar  = (const float*)d_in[4];
    const float* bnw   = (const float*)d_in[5];
    const float* bnb   = (const float*)d_in[6];
    const float* scl   = (const float*)d_in[7];
    float* out = (float*)d_out;

    char* ws = (char*)d_ws;
    uint32_t*       xt    = (uint32_t*)ws;                       // 64 MiB NHWC bf16 (swizzled)
    unsigned short* Wb    = (unsigned short*)(ws + 67108864);    // 147456 B (swizzled)
    float*          alpha = (float*)(ws + 67108864 + 147456);    // 512 B
    float*          beta  = alpha + 128;                         // 512 B

    (void)hipFuncSetAttribute((const void*)conv_main_kernel,
                              hipFuncAttributeMaxDynamicSharedMemorySize, LDSSZ);

    xpose_kernel<<<32 * 128, 256, 0, stream>>>(x, xt);
    wprep_kernel<<<128, 64, 0, stream>>>(Wt, Bb, rmean, rvar, bnw, bnb, scl,
                                         Wb, alpha, beta);
    conv_main_kernel<<<NBLK, 256, LDSSZ, stream>>>((const char*)xt, (const char*)Wb,
                                                   alpha, beta, out);
}